// Round 1
// baseline (26170.099 us; speedup 1.0000x reference)
//
#include <hip/hip_runtime.h>
#include <cstddef>

#define DEV __device__ __forceinline__

DEV float bf2f(unsigned int u){ return __uint_as_float(u << 16); }
DEV unsigned short f2bf(float f){
  unsigned int x = __float_as_uint(f);
  x += 0x7fffu + ((x >> 16) & 1u);
  return (unsigned short)(x >> 16);
}

// ---------------- weight pre-transpose: out[c][r] = in[r][c] ----------------
__global__ void transpose_k(const float* __restrict__ in, float* __restrict__ out, int R, int C){
  int idx = blockIdx.x * 256 + threadIdx.x;
  if (idx < R * C){
    int r = idx / C, c = idx - r * C;
    out[c * R + r] = in[idx];
  }
}

// ---------------- GroupNorm stage 1: per-(b,c) plane sums ----------------
__global__ void gn_partial(const float* __restrict__ x, float* __restrict__ part){
  int bc = blockIdx.x, tid = threadIdx.x;
  const float4* p = (const float4*)(x + (size_t)bc * 16384);
  float s = 0.f, s2 = 0.f;
  for (int i = tid; i < 4096; i += 256){
    float4 v = p[i];
    s  += v.x + v.y + v.z + v.w;
    s2 += v.x*v.x + v.y*v.y + v.z*v.z + v.w*v.w;
  }
  #pragma unroll
  for (int off = 32; off; off >>= 1){ s += __shfl_down(s, off); s2 += __shfl_down(s2, off); }
  __shared__ float red[8];
  int wid = tid >> 6;
  if ((tid & 63) == 0){ red[wid*2] = s; red[wid*2+1] = s2; }
  __syncthreads();
  if (tid == 0){
    part[bc*2]   = red[0] + red[2] + red[4] + red[6];
    part[bc*2+1] = red[1] + red[3] + red[5] + red[7];
  }
}

// ---------------- GroupNorm stage 2: per-sample mean/rstd ----------------
__global__ void gn_final(const float* __restrict__ part, float* __restrict__ stats){
  int b = blockIdx.x, tid = threadIdx.x;
  float s = 0.f, s2 = 0.f;
  for (int c = tid; c < 192; c += 64){
    s  += part[(b*192 + c)*2];
    s2 += part[(b*192 + c)*2 + 1];
  }
  #pragma unroll
  for (int off = 32; off; off >>= 1){ s += __shfl_down(s, off); s2 += __shfl_down(s2, off); }
  if (tid == 0){
    const float inv = 1.f / (192.f * 16384.f);
    float mean = s * inv;
    float var  = s2 * inv - mean*mean;
    stats[b*2]   = mean;
    stats[b*2+1] = rsqrtf(var + 1e-5f);
  }
}

// ---------------- GN apply + NCHW -> NHWC transpose (xb = residual base) ----------------
__global__ void gn_apply(const float* __restrict__ x, const float* __restrict__ stats,
                         const float* __restrict__ gnw, const float* __restrict__ gnb,
                         float* __restrict__ xb){
  __shared__ float tile[192*64];
  int blk = blockIdx.x, tid = threadIdx.x;
  int b = blk >> 8, p0 = (blk & 255) * 64;
  float mean = stats[b*2], rstd = stats[b*2+1];
  #pragma unroll 1
  for (int i = 0; i < 12; i++){
    int idx4 = i*256 + tid;
    int c = idx4 >> 4, pq = idx4 & 15;
    float4 v = *(const float4*)(x + (((size_t)b*192 + c) << 14) + p0 + pq*4);
    float w  = gnw[c] * rstd;
    float bb = gnb[c] - mean * rstd * gnw[c];
    int pb_ = pq*4;
    tile[c*64 + ((pb_     + c) & 63)] = v.x * w + bb;
    tile[c*64 + ((pb_ + 1 + c) & 63)] = v.y * w + bb;
    tile[c*64 + ((pb_ + 2 + c) & 63)] = v.z * w + bb;
    tile[c*64 + ((pb_ + 3 + c) & 63)] = v.w * w + bb;
  }
  __syncthreads();
  #pragma unroll 1
  for (int i = 0; i < 12; i++){
    int idx4 = i*256 + tid;
    int pix = idx4 / 48, c4 = idx4 - pix*48;
    int cb = c4 * 4;
    float4 o;
    o.x = tile[(cb  )*64 + ((pix + cb    ) & 63)];
    o.y = tile[(cb+1)*64 + ((pix + cb + 1) & 63)];
    o.z = tile[(cb+2)*64 + ((pix + cb + 2) & 63)];
    o.w = tile[(cb+3)*64 + ((pix + cb + 3) & 63)];
    *(float4*)(xb + ((size_t)blk*64 + pix)*192 + cb) = o;
  }
}

// ---------------- fused window attention: LN1 + shift + qkv + attn + proj + shortcut ----------------
__launch_bounds__(256)
__global__ void attn_kernel(const float* __restrict__ xb, float* __restrict__ xb2,
                            const float* __restrict__ ln1w, const float* __restrict__ ln1b,
                            const float* __restrict__ qkvT, const float* __restrict__ qkvb,
                            const float* __restrict__ projT, const float* __restrict__ projb,
                            const float* __restrict__ rpb){
  __shared__ __align__(16) unsigned char smem[58624];
  unsigned int*   h32     = (unsigned int*)smem;               // [64][96] bf16x2, swizzled
  float*          qkvs    = (float*)(smem + 24576);            // [3][64][32], swizzled
  unsigned short* attns   = (unsigned short*)(smem + 49152);   // [64][64] bf16, swizzled
  float*          ctxh    = (float*)(smem + 49152);            // alias: per-head ctx [64][32]
  float*          rpbs    = (float*)(smem + 57344);            // [225]
  int*            regions = (int*)(smem + 58304);              // [64]

  const int tid = threadIdx.x;
  const int t = tid >> 2, q4 = tid & 3;
  const int blk = blockIdx.x;
  const int b = blk >> 8, wloc = blk & 255, wh = wloc >> 4, ww = wloc & 15;
  const int r = t >> 3, cc = t & 7;
  const int sh = (wh*8 + r + 4) & 127, sw = (ww*8 + cc + 4) & 127;
  const float* xrow = xb + (size_t)((((b << 7) + sh) << 7) + sw) * 192;
  const int c0 = q4 * 48;

  // ---- LN1 over 192 channels (4 threads per token) ----
  float s = 0.f, s2 = 0.f;
  float4 xv[12];
  #pragma unroll
  for (int i = 0; i < 12; i++){
    xv[i] = *(const float4*)(xrow + c0 + i*4);
    s  += xv[i].x + xv[i].y + xv[i].z + xv[i].w;
    s2 += xv[i].x*xv[i].x + xv[i].y*xv[i].y + xv[i].z*xv[i].z + xv[i].w*xv[i].w;
  }
  s  += __shfl_xor(s, 1);  s  += __shfl_xor(s, 2);
  s2 += __shfl_xor(s2, 1); s2 += __shfl_xor(s2, 2);
  const float mean = s * (1.f/192.f);
  const float rstd = rsqrtf(s2 * (1.f/192.f) - mean*mean + 1e-5f);
  #pragma unroll
  for (int i = 0; i < 12; i++){
    int cb = c0 + i*4;
    float h0 = (xv[i].x - mean) * rstd * ln1w[cb  ] + ln1b[cb  ];
    float h1 = (xv[i].y - mean) * rstd * ln1w[cb+1] + ln1b[cb+1];
    float h2 = (xv[i].z - mean) * rstd * ln1w[cb+2] + ln1b[cb+2];
    float h3 = (xv[i].w - mean) * rstd * ln1w[cb+3] + ln1b[cb+3];
    int j0 = cb >> 1;
    int a0 = j0 + t;     if (a0 >= 96) a0 -= 96;
    int a1 = j0 + 1 + t; if (a1 >= 96) a1 -= 96;
    h32[t*96 + a0] = (unsigned int)f2bf(h0) | ((unsigned int)f2bf(h1) << 16);
    h32[t*96 + a1] = (unsigned int)f2bf(h2) | ((unsigned int)f2bf(h3) << 16);
  }
  if (q4 == 0){
    int gh = wh*8 + r, gw = ww*8 + cc;
    regions[t] = (gh < 120 ? 0 : (gh < 124 ? 1 : 2)) * 3 + (gw < 120 ? 0 : (gw < 124 ? 1 : 2));
  }

  // persistent projection accumulators: outputs c = c0 + k4*4 + e for token t
  float4 acc4[12];
  #pragma unroll
  for (int k4 = 0; k4 < 12; k4++) acc4[k4] = *(const float4*)(projb + c0 + k4*4);

  const int ri = t >> 3, ci = t & 7;
  const float scale = 0.17677669529663687f; // 32^-0.5

  #pragma unroll 1
  for (int hh = 0; hh < 6; hh++){
    __syncthreads();
    if (tid < 225) rpbs[tid] = rpb[tid*6 + hh];
    // ---- q,k,v for this head ----
    #pragma unroll 1
    for (int o = 0; o < 24; o++){
      int gi = o*256 + tid;
      int which = gi >> 11;
      int rem = gi & 2047;
      int tt = rem >> 5, d = rem & 31;
      int col = which*192 + hh*32 + d;
      const float2* wr = (const float2*)(qkvT + (size_t)col * 192);
      const unsigned int* hrow = h32 + tt*96;
      float acc = qkvb[col];
      #pragma unroll 4
      for (int j = 0; j < 96; j++){
        int jj = j + tt; if (jj >= 96) jj -= 96;
        unsigned int hv = hrow[jj];
        float2 w2 = wr[j];
        acc = fmaf(bf2f(hv & 0xffffu), w2.x, acc);
        acc = fmaf(bf2f(hv >> 16),     w2.y, acc);
      }
      if (which == 0) acc *= scale;
      qkvs[which*2048 + tt*32 + ((d + tt) & 31)] = acc;
    }
    __syncthreads();
    // ---- QK^T + bias + mask ----
    {
      int regi = regions[t];
      #pragma unroll 1
      for (int m = 0; m < 16; m++){
        int j = q4*16 + m;
        float acc = 0.f;
        #pragma unroll
        for (int d = 0; d < 32; d++){
          acc = fmaf(qkvs[t*32 + ((d + t) & 31)], qkvs[2048 + j*32 + ((d + j) & 31)], acc);
        }
        int rj = j >> 3, cj = j & 7;
        float logit = acc + rpbs[(ri - rj + 7)*15 + (ci - cj + 7)]
                          + ((regi == regions[j]) ? 0.f : -100.f);
        attns[t*64 + ((j + 2*t) & 63)] = f2bf(logit);
      }
    }
    __syncthreads();
    // ---- softmax (one thread per row) ----
    if (tid < 64){
      int base = tid*64, o2 = 2*tid;
      float mx = -3.0e38f;
      #pragma unroll 1
      for (int j = 0; j < 64; j++) mx = fmaxf(mx, bf2f((unsigned int)attns[base + ((j + o2) & 63)]));
      float sum = 0.f;
      #pragma unroll 1
      for (int j = 0; j < 64; j++){
        int a = base + ((j + o2) & 63);
        float e = __expf(bf2f((unsigned int)attns[a]) - mx);
        sum += e;
        attns[a] = f2bf(e);
      }
      float inv = 1.f / sum;
      #pragma unroll 1
      for (int j = 0; j < 64; j++){
        int a = base + ((j + o2) & 63);
        attns[a] = f2bf(bf2f((unsigned int)attns[a]) * inv);
      }
    }
    __syncthreads();
    // ---- PV ----
    float ctx8[8];
    #pragma unroll
    for (int dd = 0; dd < 8; dd++) ctx8[dd] = 0.f;
    #pragma unroll 2
    for (int j = 0; j < 64; j++){
      float p = bf2f((unsigned int)attns[t*64 + ((j + 2*t) & 63)]);
      const float* vrow = qkvs + 4096 + j*32;
      #pragma unroll
      for (int dd = 0; dd < 8; dd++){
        ctx8[dd] = fmaf(p, vrow[(q4*8 + dd + j) & 31], ctx8[dd]);
      }
    }
    __syncthreads();
    // ---- share ctx of this head (reuse attns region) ----
    #pragma unroll
    for (int dd = 0; dd < 8; dd++){
      ctxh[t*32 + ((q4*8 + dd + t) & 31)] = ctx8[dd];
    }
    __syncthreads();
    // ---- incremental projection over this head's 32 channels ----
    #pragma unroll 1
    for (int dq = 0; dq < 8; dq++){
      float cv0 = ctxh[t*32 + ((dq*4     + t) & 31)];
      float cv1 = ctxh[t*32 + ((dq*4 + 1 + t) & 31)];
      float cv2 = ctxh[t*32 + ((dq*4 + 2 + t) & 31)];
      float cv3 = ctxh[t*32 + ((dq*4 + 3 + t) & 31)];
      int cpb = hh*32 + dq*4;
      #pragma unroll
      for (int k4 = 0; k4 < 12; k4++){
        const float* wb = projT + (size_t)(c0 + k4*4) * 192 + cpb;
        float4 w0 = *(const float4*)(wb);
        float4 w1 = *(const float4*)(wb + 192);
        float4 w2 = *(const float4*)(wb + 384);
        float4 w3 = *(const float4*)(wb + 576);
        acc4[k4].x += cv0*w0.x + cv1*w0.y + cv2*w0.z + cv3*w0.w;
        acc4[k4].y += cv0*w1.x + cv1*w1.y + cv2*w1.z + cv3*w1.w;
        acc4[k4].z += cv0*w2.x + cv1*w2.y + cv2*w2.z + cv3*w2.w;
        acc4[k4].w += cv0*w3.x + cv1*w3.y + cv2*w3.z + cv3*w3.w;
      }
    }
  }
  // ---- xb2 = shortcut + proj out (dest position == gather position) ----
  float* orow = xb2 + (size_t)((((b << 7) + sh) << 7) + sw) * 192;
  #pragma unroll
  for (int k4 = 0; k4 < 12; k4++){
    float4 xr = *(const float4*)(xrow + c0 + k4*4);
    float4 o;
    o.x = xr.x + acc4[k4].x;
    o.y = xr.y + acc4[k4].y;
    o.z = xr.z + acc4[k4].z;
    o.w = xr.w + acc4[k4].w;
    *(float4*)(orow + c0 + k4*4) = o;
  }
}

// ---------------- fused MLP: LN2 + fc1 + GELU + fc2 + both residuals (in-place xb2) ----------------
__launch_bounds__(256)
__global__ void mlp_kernel(const float* __restrict__ xb, float* __restrict__ xb2,
                           const float* __restrict__ ln2w, const float* __restrict__ ln2b,
                           const float* __restrict__ fc1T, const float* __restrict__ fc1b,
                           const float* __restrict__ fc2T, const float* __restrict__ fc2b){
  __shared__ unsigned int aln[64*96];   // LN2 output, bf16x2, swizzled
  __shared__ float hids[64*64];         // hidden chunk, swizzled
  const int tid = threadIdx.x;
  const int t = tid >> 2, q4 = tid & 3;
  const size_t p = (size_t)blockIdx.x*64 + t;
  const float* xrow2 = xb2 + p*192;
  const float* xrow  = xb  + p*192;
  const int c0 = q4 * 48;

  float s = 0.f, s2 = 0.f;
  float4 xv[12];
  #pragma unroll
  for (int i = 0; i < 12; i++){
    xv[i] = *(const float4*)(xrow2 + c0 + i*4);
    s  += xv[i].x + xv[i].y + xv[i].z + xv[i].w;
    s2 += xv[i].x*xv[i].x + xv[i].y*xv[i].y + xv[i].z*xv[i].z + xv[i].w*xv[i].w;
  }
  s  += __shfl_xor(s, 1);  s  += __shfl_xor(s, 2);
  s2 += __shfl_xor(s2, 1); s2 += __shfl_xor(s2, 2);
  const float mean = s * (1.f/192.f);
  const float rstd = rsqrtf(s2 * (1.f/192.f) - mean*mean + 1e-5f);
  #pragma unroll
  for (int i = 0; i < 12; i++){
    int cb = c0 + i*4;
    float h0 = (xv[i].x - mean) * rstd * ln2w[cb  ] + ln2b[cb  ];
    float h1 = (xv[i].y - mean) * rstd * ln2w[cb+1] + ln2b[cb+1];
    float h2 = (xv[i].z - mean) * rstd * ln2w[cb+2] + ln2b[cb+2];
    float h3 = (xv[i].w - mean) * rstd * ln2w[cb+3] + ln2b[cb+3];
    int j0 = cb >> 1;
    int a0 = j0 + t;     if (a0 >= 96) a0 -= 96;
    int a1 = j0 + 1 + t; if (a1 >= 96) a1 -= 96;
    aln[t*96 + a0] = (unsigned int)f2bf(h0) | ((unsigned int)f2bf(h1) << 16);
    aln[t*96 + a1] = (unsigned int)f2bf(h2) | ((unsigned int)f2bf(h3) << 16);
  }
  // acc = xb2 + xb + fc2_b  (both residuals folded in)
  float4 acc4[12];
  #pragma unroll
  for (int i = 0; i < 12; i++){
    int cb = c0 + i*4;
    float4 xr = *(const float4*)(xrow + cb);
    float4 fb = *(const float4*)(fc2b + cb);
    acc4[i].x = xv[i].x + xr.x + fb.x;
    acc4[i].y = xv[i].y + xr.y + fb.y;
    acc4[i].z = xv[i].z + xr.z + fb.z;
    acc4[i].w = xv[i].w + xr.w + fb.w;
  }
  #pragma unroll 1
  for (int ch = 0; ch < 12; ch++){
    __syncthreads();
    // fc1 + exact GELU for 64-wide hidden chunk
    #pragma unroll 1
    for (int m = 0; m < 16; m++){
      int hl = q4*16 + m;
      int hrow = ch*64 + hl;
      const float2* wr = (const float2*)(fc1T + (size_t)hrow * 192);
      const unsigned int* arow = aln + t*96;
      float a = fc1b[hrow];
      #pragma unroll 4
      for (int j = 0; j < 96; j++){
        int jj = j + t; if (jj >= 96) jj -= 96;
        unsigned int hv = arow[jj];
        float2 w2 = wr[j];
        a = fmaf(bf2f(hv & 0xffffu), w2.x, a);
        a = fmaf(bf2f(hv >> 16),     w2.y, a);
      }
      float g = 0.5f * a * (1.f + erff(a * 0.7071067811865475f));
      hids[t*64 + ((hl + t) & 63)] = g;
    }
    __syncthreads();
    // fc2 accumulate
    #pragma unroll 1
    for (int j4 = 0; j4 < 16; j4++){
      int jb = j4*4;
      float hv0 = hids[t*64 + ((jb     + t) & 63)];
      float hv1 = hids[t*64 + ((jb + 1 + t) & 63)];
      float hv2 = hids[t*64 + ((jb + 2 + t) & 63)];
      float hv3 = hids[t*64 + ((jb + 3 + t) & 63)];
      #pragma unroll
      for (int k4 = 0; k4 < 12; k4++){
        const float* wb = fc2T + (size_t)(c0 + k4*4) * 768 + ch*64 + jb;
        float4 w0 = *(const float4*)(wb);
        float4 w1 = *(const float4*)(wb + 768);
        float4 w2 = *(const float4*)(wb + 1536);
        float4 w3 = *(const float4*)(wb + 2304);
        acc4[k4].x += hv0*w0.x + hv1*w0.y + hv2*w0.z + hv3*w0.w;
        acc4[k4].y += hv0*w1.x + hv1*w1.y + hv2*w1.z + hv3*w1.w;
        acc4[k4].z += hv0*w2.x + hv1*w2.y + hv2*w2.z + hv3*w2.w;
        acc4[k4].w += hv0*w3.x + hv1*w3.y + hv2*w3.z + hv3*w3.w;
      }
    }
  }
  float* orow = xb2 + p*192;
  #pragma unroll
  for (int k4 = 0; k4 < 12; k4++){
    *(float4*)(orow + c0 + k4*4) = acc4[k4];
  }
}

// ---------------- final NHWC -> NCHW transpose + clamp ----------------
__global__ void final_k(const float* __restrict__ xb2, float* __restrict__ out){
  __shared__ float tile[192*64];
  int blk = blockIdx.x, tid = threadIdx.x;
  int b = blk >> 8, p0 = (blk & 255) * 64;
  #pragma unroll 1
  for (int i = 0; i < 12; i++){
    int idx4 = i*256 + tid;
    int tt = idx4 / 48, c4 = idx4 - tt*48;
    int cb = c4 * 4;
    float4 v = *(const float4*)(xb2 + ((size_t)blk*64 + tt)*192 + cb);
    tile[(cb  )*64 + ((tt + cb    ) & 63)] = v.x;
    tile[(cb+1)*64 + ((tt + cb + 1) & 63)] = v.y;
    tile[(cb+2)*64 + ((tt + cb + 2) & 63)] = v.z;
    tile[(cb+3)*64 + ((tt + cb + 3) & 63)] = v.w;
  }
  __syncthreads();
  #pragma unroll 1
  for (int i = 0; i < 12; i++){
    int idx4 = i*256 + tid;
    int c = idx4 >> 4, pq = idx4 & 15;
    int pb_ = pq*4;
    float4 o;
    o.x = tile[c*64 + ((pb_     + c) & 63)];
    o.y = tile[c*64 + ((pb_ + 1 + c) & 63)];
    o.z = tile[c*64 + ((pb_ + 2 + c) & 63)];
    o.w = tile[c*64 + ((pb_ + 3 + c) & 63)];
    o.x = fminf(fmaxf(o.x, -10.f), 10.f);
    o.y = fminf(fmaxf(o.y, -10.f), 10.f);
    o.z = fminf(fmaxf(o.z, -10.f), 10.f);
    o.w = fminf(fmaxf(o.w, -10.f), 10.f);
    *(float4*)(out + (((size_t)b*192 + c) << 14) + p0 + pb_) = o;
  }
}

extern "C" void kernel_launch(void* const* d_in, const int* in_sizes, int n_in,
                              void* d_out, int out_size, void* d_ws, size_t ws_size,
                              hipStream_t stream){
  (void)in_sizes; (void)n_in; (void)out_size; (void)ws_size;
  const float* x     = (const float*)d_in[0];
  const float* gnw   = (const float*)d_in[1];
  const float* gnb   = (const float*)d_in[2];
  const float* ln1w  = (const float*)d_in[3];
  const float* ln1b  = (const float*)d_in[4];
  const float* qkvw  = (const float*)d_in[5];
  const float* qkvb  = (const float*)d_in[6];
  const float* projw = (const float*)d_in[7];
  const float* projb = (const float*)d_in[8];
  const float* rpb   = (const float*)d_in[9];
  const float* ln2w  = (const float*)d_in[10];
  const float* ln2b  = (const float*)d_in[11];
  const float* fc1w  = (const float*)d_in[12];
  const float* fc1b  = (const float*)d_in[13];
  const float* fc2w  = (const float*)d_in[14];
  const float* fc2b  = (const float*)d_in[15];
  float* out = (float*)d_out;

  float* ws    = (float*)d_ws;
  float* xb2   = ws;                      // [B,H,W,C]  25,165,824 f
  float* part  = xb2  + 25165824;         // [B*C][2]
  float* stats = part + 3072;             // [B][2]
  float* qkvT  = stats + 16;              // [576][192]
  float* projT = qkvT + 110592;           // [192][192]
  float* fc1T  = projT + 36864;           // [768][192]
  float* fc2T  = fc1T + 147456;           // [192][768]
  float* xb    = out;                     // residual base lives in d_out until final_k rewrites it

  transpose_k<<<432, 256, 0, stream>>>(qkvw, qkvT, 192, 576);
  transpose_k<<<144, 256, 0, stream>>>(projw, projT, 192, 192);
  transpose_k<<<576, 256, 0, stream>>>(fc1w, fc1T, 192, 768);
  transpose_k<<<576, 256, 0, stream>>>(fc2w, fc2T, 768, 192);
  gn_partial<<<1536, 256, 0, stream>>>(x, part);
  gn_final<<<8, 64, 0, stream>>>(part, stats);
  gn_apply<<<2048, 256, 0, stream>>>(x, stats, gnw, gnb, xb);
  attn_kernel<<<2048, 256, 0, stream>>>(xb, xb2, ln1w, ln1b, qkvT, qkvb, projT, projb, rpb);
  mlp_kernel<<<2048, 256, 0, stream>>>(xb, xb2, ln2w, ln2b, fc1T, fc1b, fc2T, fc2b);
  final_k<<<2048, 256, 0, stream>>>(xb2, out);
}

// Round 3
// 1273.592 us; speedup vs baseline: 20.5483x; 20.5483x over previous
//
#include <hip/hip_runtime.h>
#include <cstddef>

typedef __attribute__((ext_vector_type(8))) short bf16x8;
typedef __attribute__((ext_vector_type(4))) float f32x4;

#define DEV __device__ __forceinline__
#define MFMA16(a,b,c) __builtin_amdgcn_mfma_f32_16x16x32_bf16((a),(b),(c),0,0,0)

DEV float bf2f(unsigned int u){ return __uint_as_float(u << 16); }
DEV unsigned short f2bf(float f){
  unsigned int x = __float_as_uint(f);
  x += 0x7fffu + ((x >> 16) & 1u);
  return (unsigned short)(x >> 16);
}
DEV unsigned int pack2(float a, float b){
  return (unsigned int)f2bf(a) | ((unsigned int)f2bf(b) << 16);
}

// ---------------- weight transpose + bf16 cast: out[n][k] = in[k][n] ----------------
__global__ void transpose_cast_k(const float* __restrict__ in, unsigned short* __restrict__ out,
                                 int K, int N){
  int idx = blockIdx.x * 256 + threadIdx.x;
  if (idx < K * N){
    int n = idx / K, k = idx - n * K;
    out[idx] = f2bf(in[k * N + n]);
  }
}

// ---------------- GroupNorm stage 1 ----------------
__global__ void gn_partial(const float* __restrict__ x, float* __restrict__ part){
  int bc = blockIdx.x, tid = threadIdx.x;
  const float4* p = (const float4*)(x + (size_t)bc * 16384);
  float s = 0.f, s2 = 0.f;
  for (int i = tid; i < 4096; i += 256){
    float4 v = p[i];
    s  += v.x + v.y + v.z + v.w;
    s2 += v.x*v.x + v.y*v.y + v.z*v.z + v.w*v.w;
  }
  #pragma unroll
  for (int off = 32; off; off >>= 1){ s += __shfl_down(s, off); s2 += __shfl_down(s2, off); }
  __shared__ float red[8];
  int wid = tid >> 6;
  if ((tid & 63) == 0){ red[wid*2] = s; red[wid*2+1] = s2; }
  __syncthreads();
  if (tid == 0){
    part[bc*2]   = red[0] + red[2] + red[4] + red[6];
    part[bc*2+1] = red[1] + red[3] + red[5] + red[7];
  }
}

// ---------------- GroupNorm stage 2 ----------------
__global__ void gn_final(const float* __restrict__ part, float* __restrict__ stats){
  int b = blockIdx.x, tid = threadIdx.x;
  float s = 0.f, s2 = 0.f;
  for (int c = tid; c < 192; c += 64){
    s  += part[(b*192 + c)*2];
    s2 += part[(b*192 + c)*2 + 1];
  }
  #pragma unroll
  for (int off = 32; off; off >>= 1){ s += __shfl_down(s, off); s2 += __shfl_down(s2, off); }
  if (tid == 0){
    const float inv = 1.f / (192.f * 16384.f);
    float mean = s * inv;
    float var  = s2 * inv - mean*mean;
    stats[b*2]   = mean;
    stats[b*2+1] = rsqrtf(var + 1e-5f);
  }
}

// ---------------- GN apply + NCHW -> NHWC ----------------
__global__ void gn_apply(const float* __restrict__ x, const float* __restrict__ stats,
                         const float* __restrict__ gnw, const float* __restrict__ gnb,
                         float* __restrict__ xb){
  __shared__ float tile[192*64];
  int blk = blockIdx.x, tid = threadIdx.x;
  int b = blk >> 8, p0 = (blk & 255) * 64;
  float mean = stats[b*2], rstd = stats[b*2+1];
  #pragma unroll 1
  for (int i = 0; i < 12; i++){
    int idx4 = i*256 + tid;
    int c = idx4 >> 4, pq = idx4 & 15;
    float4 v = *(const float4*)(x + (((size_t)b*192 + c) << 14) + p0 + pq*4);
    float w  = gnw[c] * rstd;
    float bb = gnb[c] - mean * rstd * gnw[c];
    int pb_ = pq*4;
    tile[c*64 + ((pb_     + c) & 63)] = v.x * w + bb;
    tile[c*64 + ((pb_ + 1 + c) & 63)] = v.y * w + bb;
    tile[c*64 + ((pb_ + 2 + c) & 63)] = v.z * w + bb;
    tile[c*64 + ((pb_ + 3 + c) & 63)] = v.w * w + bb;
  }
  __syncthreads();
  #pragma unroll 1
  for (int i = 0; i < 12; i++){
    int idx4 = i*256 + tid;
    int pix = idx4 / 48, c4 = idx4 - pix*48;
    int cb = c4 * 4;
    float4 o;
    o.x = tile[(cb  )*64 + ((pix + cb    ) & 63)];
    o.y = tile[(cb+1)*64 + ((pix + cb + 1) & 63)];
    o.z = tile[(cb+2)*64 + ((pix + cb + 2) & 63)];
    o.w = tile[(cb+3)*64 + ((pix + cb + 3) & 63)];
    *(float4*)(xb + ((size_t)blk*64 + pix)*192 + cb) = o;
  }
}

// ---------------- fused window attention (MFMA) ----------------
__launch_bounds__(256)
__global__ void attn_kernel(const float* __restrict__ xb, float* __restrict__ xb2,
                            const float* __restrict__ ln1w, const float* __restrict__ ln1b,
                            const unsigned short* __restrict__ qkvB, const float* __restrict__ qkvb,
                            const unsigned short* __restrict__ projB, const float* __restrict__ projb,
                            const float* __restrict__ rpb){
  __shared__ unsigned short h16[64*192];        // LN1 out bf16 [token][c]
  __shared__ unsigned short qk16[2][2][64*40];  // [q/k][head][token*40+d]
  __shared__ unsigned short vT16[2][32*72];     // [head][d*72+token]
  __shared__ unsigned short ps16[64*72];        // probs [token][j]; cols 0..31 reused as ctx
  __shared__ int regions[64];

  const int tid = threadIdx.x;
  const int blk = blockIdx.x;
  const int b = blk >> 8, wloc = blk & 255, wh = wloc >> 4, ww = wloc & 15;
  const int lane = tid & 63, wv = tid >> 6;
  const int ln15 = lane & 15, l16 = lane >> 4;
  const f32x4 zero4 = {0.f, 0.f, 0.f, 0.f};

  // ---- LN1 (thread t = token, q4 = channel quarter) ----
  {
    const int t = tid >> 2, q4 = tid & 3, c0 = q4 * 48;
    const int tr = t >> 3, tc = t & 7;
    const int sh = (wh*8 + tr + 4) & 127, sw = (ww*8 + tc + 4) & 127;
    const float* xrow = xb + (size_t)((((b << 7) + sh) << 7) + sw) * 192;
    float s = 0.f, s2 = 0.f;
    float4 xv[12];
    #pragma unroll
    for (int i = 0; i < 12; i++){
      xv[i] = *(const float4*)(xrow + c0 + i*4);
      s  += xv[i].x + xv[i].y + xv[i].z + xv[i].w;
      s2 += xv[i].x*xv[i].x + xv[i].y*xv[i].y + xv[i].z*xv[i].z + xv[i].w*xv[i].w;
    }
    s  += __shfl_xor(s, 1);  s  += __shfl_xor(s, 2);
    s2 += __shfl_xor(s2, 1); s2 += __shfl_xor(s2, 2);
    const float mean = s * (1.f/192.f);
    const float rstd = rsqrtf(s2 * (1.f/192.f) - mean*mean + 1e-5f);
    #pragma unroll
    for (int i = 0; i < 12; i++){
      int cb = c0 + i*4;
      float v0 = (xv[i].x - mean) * rstd * ln1w[cb  ] + ln1b[cb  ];
      float v1 = (xv[i].y - mean) * rstd * ln1w[cb+1] + ln1b[cb+1];
      float v2 = (xv[i].z - mean) * rstd * ln1w[cb+2] + ln1b[cb+2];
      float v3 = (xv[i].w - mean) * rstd * ln1w[cb+3] + ln1b[cb+3];
      unsigned int* dst = (unsigned int*)(h16 + t*192 + cb);
      dst[0] = pack2(v0, v1);
      dst[1] = pack2(v2, v3);
    }
    if (q4 == 0){
      int gh = wh*8 + tr, gw = ww*8 + tc;
      regions[t] = (gh < 120 ? 0 : (gh < 124 ? 1 : 2)) * 3 + (gw < 120 ? 0 : (gw < 124 ? 1 : 2));
    }
  }
  __syncthreads();

  f32x4 pacc[4][3];
  #pragma unroll
  for (int mt = 0; mt < 4; mt++)
    #pragma unroll
    for (int nt = 0; nt < 3; nt++)
      pacc[mt][nt] = zero4;

  const float scale = 0.17677669529663687f;

  #pragma unroll 1
  for (int hp = 0; hp < 3; hp++){
    const int h0 = hp * 2;
    // ---- phase a: qkv for heads h0,h0+1 (192 cols = 12 tiles; wave does 3) ----
    f32x4 qacc[3][4];
    #pragma unroll
    for (int tt0 = 0; tt0 < 3; tt0++)
      #pragma unroll
      for (int mt = 0; mt < 4; mt++)
        qacc[tt0][mt] = zero4;

    #pragma unroll 1
    for (int tt0 = 0; tt0 < 3; tt0++){
      int tt = wv*3 + tt0;
      int which = tt >> 2, sub = tt & 3;
      int colb = which*192 + h0*32 + sub*16;
      const unsigned short* bp = qkvB + (size_t)(colb + ln15)*192 + l16*8;
      bf16x8 bw[6];
      #pragma unroll
      for (int ks = 0; ks < 6; ks++) bw[ks] = *(const bf16x8*)(bp + ks*32);
      #pragma unroll
      for (int mt = 0; mt < 4; mt++){
        const unsigned short* ap = h16 + (mt*16 + ln15)*192 + l16*8;
        #pragma unroll
        for (int ks = 0; ks < 6; ks++){
          bf16x8 af = *(const bf16x8*)(ap + ks*32);
          qacc[tt0][mt] = MFMA16(af, bw[ks], qacc[tt0][mt]);
        }
      }
    }
    // epilogue: + bias, scatter to q/k/vT LDS (q scaled)
    #pragma unroll 1
    for (int tt0 = 0; tt0 < 3; tt0++){
      int tt = wv*3 + tt0;
      int which = tt >> 2, sub = tt & 3;
      int colg = which*192 + h0*32 + sub*16 + ln15;
      float bias = qkvb[colg];
      int local = sub*16 + ln15;
      int hl = local >> 5, d = local & 31;
      #pragma unroll
      for (int mt = 0; mt < 4; mt++){
        #pragma unroll
        for (int reg = 0; reg < 4; reg++){
          float v = qacc[tt0][mt][reg] + bias;
          int token = mt*16 + l16*4 + reg;
          if (which == 0)      qk16[0][hl][token*40 + d] = f2bf(v * scale);
          else if (which == 1) qk16[1][hl][token*40 + d] = f2bf(v);
          else                 vT16[hl][d*72 + token]    = f2bf(v);
        }
      }
    }
    __syncthreads();

    #pragma unroll 1
    for (int e = 0; e < 2; e++){
      const int h = h0 + e;
      // ---- S = q k^T (wave handles row-tile wv, 4 col-tiles, K=32) ----
      f32x4 sacc[4];
      bf16x8 aq = *(const bf16x8*)(&qk16[0][e][(wv*16 + ln15)*40 + l16*8]);
      #pragma unroll
      for (int nt = 0; nt < 4; nt++){
        bf16x8 bk = *(const bf16x8*)(&qk16[1][e][(nt*16 + ln15)*40 + l16*8]);
        sacc[nt] = MFMA16(aq, bk, zero4);
      }
      // ---- bias + mask ----
      #pragma unroll
      for (int nt = 0; nt < 4; nt++){
        int j_tok = nt*16 + ln15;
        int rj = j_tok >> 3, cj = j_tok & 7;
        int regj = regions[j_tok];
        #pragma unroll
        for (int reg = 0; reg < 4; reg++){
          int i_tok = wv*16 + l16*4 + reg;
          int ri = i_tok >> 3, ci = i_tok & 7;
          float bias = rpb[((ri - rj + 7)*15 + (ci - cj + 7))*6 + h];
          float v = sacc[nt][reg] + bias + ((regions[i_tok] == regj) ? 0.f : -100.f);
          sacc[nt][reg] = v;
        }
      }
      // ---- softmax across 16 lanes (cols) x 4 nt, per reg ----
      float mx[4], sum[4];
      #pragma unroll
      for (int reg = 0; reg < 4; reg++){
        float m = fmaxf(fmaxf(sacc[0][reg], sacc[1][reg]), fmaxf(sacc[2][reg], sacc[3][reg]));
        m = fmaxf(m, __shfl_xor(m, 1));
        m = fmaxf(m, __shfl_xor(m, 2));
        m = fmaxf(m, __shfl_xor(m, 4));
        m = fmaxf(m, __shfl_xor(m, 8));
        mx[reg] = m;
        sum[reg] = 0.f;
      }
      #pragma unroll
      for (int nt = 0; nt < 4; nt++)
        #pragma unroll
        for (int reg = 0; reg < 4; reg++){
          float ex = __expf(sacc[nt][reg] - mx[reg]);
          sacc[nt][reg] = ex;
          sum[reg] += ex;
        }
      #pragma unroll
      for (int reg = 0; reg < 4; reg++){
        float sm = sum[reg];
        sm += __shfl_xor(sm, 1);
        sm += __shfl_xor(sm, 2);
        sm += __shfl_xor(sm, 4);
        sm += __shfl_xor(sm, 8);
        sum[reg] = 1.f / sm;
      }
      // ---- write P (own rows) ----
      #pragma unroll
      for (int nt = 0; nt < 4; nt++)
        #pragma unroll
        for (int reg = 0; reg < 4; reg++)
          ps16[(wv*16 + l16*4 + reg)*72 + nt*16 + ln15] = f2bf(sacc[nt][reg] * sum[reg]);
      // ---- PV (K=64 -> 2 ks steps; 2 col-tiles of d) ----
      f32x4 cacc[2];
      #pragma unroll
      for (int nt2 = 0; nt2 < 2; nt2++) cacc[nt2] = zero4;
      #pragma unroll
      for (int ks = 0; ks < 2; ks++){
        bf16x8 ap = *(const bf16x8*)(&ps16[(wv*16 + ln15)*72 + ks*32 + l16*8]);
        #pragma unroll
        for (int nt2 = 0; nt2 < 2; nt2++){
          bf16x8 bv = *(const bf16x8*)(&vT16[e][(nt2*16 + ln15)*72 + ks*32 + l16*8]);
          cacc[nt2] = MFMA16(ap, bv, cacc[nt2]);
        }
      }
      // ---- ctx into ps cols 0..31 (own rows; own P no longer needed) ----
      #pragma unroll
      for (int nt2 = 0; nt2 < 2; nt2++)
        #pragma unroll
        for (int reg = 0; reg < 4; reg++)
          ps16[(wv*16 + l16*4 + reg)*72 + nt2*16 + ln15] = f2bf(cacc[nt2][reg]);
      __syncthreads();
      // ---- proj accumulate: out cols [wv*48, +48), K = this head's 32 dims ----
      bf16x8 bw3[3];
      #pragma unroll
      for (int nt3 = 0; nt3 < 3; nt3++)
        bw3[nt3] = *(const bf16x8*)(projB + (size_t)(wv*48 + nt3*16 + ln15)*192 + h*32 + l16*8);
      #pragma unroll
      for (int mt = 0; mt < 4; mt++){
        bf16x8 ac = *(const bf16x8*)(&ps16[(mt*16 + ln15)*72 + l16*8]);
        #pragma unroll
        for (int nt3 = 0; nt3 < 3; nt3++)
          pacc[mt][nt3] = MFMA16(ac, bw3[nt3], pacc[mt][nt3]);
      }
      __syncthreads();
    }
  }
  // ---- epilogue: xb2 = shortcut + proj + projb at shifted positions ----
  #pragma unroll 1
  for (int nt3 = 0; nt3 < 3; nt3++){
    int col = wv*48 + nt3*16 + ln15;
    float pb = projb[col];
    #pragma unroll
    for (int mt = 0; mt < 4; mt++){
      #pragma unroll
      for (int reg = 0; reg < 4; reg++){
        int token = mt*16 + l16*4 + reg;
        int r2 = token >> 3, c2 = token & 7;
        int sh2 = (wh*8 + r2 + 4) & 127, sw2 = (ww*8 + c2 + 4) & 127;
        size_t p = (size_t)((((b << 7) + sh2) << 7) + sw2) * 192 + col;
        xb2[p] = xb[p] + pacc[mt][nt3][reg] + pb;
      }
    }
  }
}

// ---------------- fused MLP (MFMA): LN2 + fc1 + GELU + fc2 + residuals ----------------
__launch_bounds__(256)
__global__ void mlp_kernel(const float* __restrict__ xb, float* __restrict__ xb2,
                           const float* __restrict__ ln2w, const float* __restrict__ ln2b,
                           const unsigned short* __restrict__ fc1B, const float* __restrict__ fc1b,
                           const unsigned short* __restrict__ fc2B, const float* __restrict__ fc2b){
  __shared__ unsigned short aln[64*192];   // LN2 out bf16
  __shared__ unsigned short hid[64*136];   // hidden chunk (128 + 8 pad)
  const int tid = threadIdx.x;
  const int lane = tid & 63, wv = tid >> 6;
  const int ln15 = lane & 15, l16 = lane >> 4;
  const size_t p0 = (size_t)blockIdx.x * 64;
  const f32x4 zero4 = {0.f, 0.f, 0.f, 0.f};

  // ---- LN2 ----
  {
    const int t = tid >> 2, q4 = tid & 3, c0 = q4 * 48;
    const float* xrow2 = xb2 + (p0 + t)*192;
    float s = 0.f, s2 = 0.f;
    float4 xv[12];
    #pragma unroll
    for (int i = 0; i < 12; i++){
      xv[i] = *(const float4*)(xrow2 + c0 + i*4);
      s  += xv[i].x + xv[i].y + xv[i].z + xv[i].w;
      s2 += xv[i].x*xv[i].x + xv[i].y*xv[i].y + xv[i].z*xv[i].z + xv[i].w*xv[i].w;
    }
    s  += __shfl_xor(s, 1);  s  += __shfl_xor(s, 2);
    s2 += __shfl_xor(s2, 1); s2 += __shfl_xor(s2, 2);
    const float mean = s * (1.f/192.f);
    const float rstd = rsqrtf(s2 * (1.f/192.f) - mean*mean + 1e-5f);
    #pragma unroll
    for (int i = 0; i < 12; i++){
      int cb = c0 + i*4;
      float v0 = (xv[i].x - mean) * rstd * ln2w[cb  ] + ln2b[cb  ];
      float v1 = (xv[i].y - mean) * rstd * ln2w[cb+1] + ln2b[cb+1];
      float v2 = (xv[i].z - mean) * rstd * ln2w[cb+2] + ln2b[cb+2];
      float v3 = (xv[i].w - mean) * rstd * ln2w[cb+3] + ln2b[cb+3];
      unsigned int* dst = (unsigned int*)(aln + t*192 + cb);
      dst[0] = pack2(v0, v1);
      dst[1] = pack2(v2, v3);
    }
  }
  __syncthreads();

  f32x4 o2[4][3];
  #pragma unroll
  for (int mt = 0; mt < 4; mt++)
    #pragma unroll
    for (int nt = 0; nt < 3; nt++)
      o2[mt][nt] = zero4;

  #pragma unroll 1
  for (int ch = 0; ch < 6; ch++){
    // ---- fc1: wave computes hidden cols [ch*128 + wv*32, +32) for all 64 tokens ----
    f32x4 f1[4][2];
    #pragma unroll
    for (int mt = 0; mt < 4; mt++)
      #pragma unroll
      for (int nt = 0; nt < 2; nt++)
        f1[mt][nt] = zero4;
    #pragma unroll 1
    for (int nt = 0; nt < 2; nt++){
      const unsigned short* bp = fc1B + (size_t)(ch*128 + wv*32 + nt*16 + ln15)*192 + l16*8;
      bf16x8 bw[6];
      #pragma unroll
      for (int ks = 0; ks < 6; ks++) bw[ks] = *(const bf16x8*)(bp + ks*32);
      #pragma unroll
      for (int mt = 0; mt < 4; mt++){
        const unsigned short* ap = aln + (mt*16 + ln15)*192 + l16*8;
        #pragma unroll
        for (int ks = 0; ks < 6; ks++){
          bf16x8 af = *(const bf16x8*)(ap + ks*32);
          f1[mt][nt] = MFMA16(af, bw[ks], f1[mt][nt]);
        }
      }
    }
    // ---- bias + GELU -> hid ----
    #pragma unroll
    for (int nt = 0; nt < 2; nt++){
      int hcol = wv*32 + nt*16 + ln15;
      float b1 = fc1b[ch*128 + hcol];
      #pragma unroll
      for (int mt = 0; mt < 4; mt++){
        #pragma unroll
        for (int reg = 0; reg < 4; reg++){
          float v = f1[mt][nt][reg] + b1;
          float g = 0.5f * v * (1.f + erff(v * 0.7071067811865475f));
          hid[(mt*16 + l16*4 + reg)*136 + hcol] = f2bf(g);
        }
      }
    }
    __syncthreads();
    // ---- fc2 partial: out cols [wv*48, +48), K = 128 chunk ----
    #pragma unroll 1
    for (int ks = 0; ks < 4; ks++){
      bf16x8 bw2[3];
      #pragma unroll
      for (int nt3 = 0; nt3 < 3; nt3++)
        bw2[nt3] = *(const bf16x8*)(fc2B + (size_t)(wv*48 + nt3*16 + ln15)*768 + ch*128 + ks*32 + l16*8);
      #pragma unroll
      for (int mt = 0; mt < 4; mt++){
        bf16x8 af = *(const bf16x8*)(&hid[(mt*16 + ln15)*136 + ks*32 + l16*8]);
        #pragma unroll
        for (int nt3 = 0; nt3 < 3; nt3++)
          o2[mt][nt3] = MFMA16(af, bw2[nt3], o2[mt][nt3]);
      }
    }
    __syncthreads();
  }
  // ---- epilogue: xb2 = xb2 + xb + fc2b + mlp ----
  #pragma unroll 1
  for (int nt3 = 0; nt3 < 3; nt3++){
    int col = wv*48 + nt3*16 + ln15;
    float fb = fc2b[col];
    #pragma unroll
    for (int mt = 0; mt < 4; mt++){
      #pragma unroll
      for (int reg = 0; reg < 4; reg++){
        int token = mt*16 + l16*4 + reg;
        size_t idx = (p0 + token)*192 + col;
        xb2[idx] = xb2[idx] + xb[idx] + fb + o2[mt][nt3][reg];
      }
    }
  }
}

// ---------------- final NHWC -> NCHW + clamp ----------------
__global__ void final_k(const float* __restrict__ xb2, float* __restrict__ out){
  __shared__ float tile[192*64];
  int blk = blockIdx.x, tid = threadIdx.x;
  int b = blk >> 8, p0 = (blk & 255) * 64;
  #pragma unroll 1
  for (int i = 0; i < 12; i++){
    int idx4 = i*256 + tid;
    int tt = idx4 / 48, c4 = idx4 - tt*48;
    int cb = c4 * 4;
    float4 v = *(const float4*)(xb2 + ((size_t)blk*64 + tt)*192 + cb);
    tile[(cb  )*64 + ((tt + cb    ) & 63)] = v.x;
    tile[(cb+1)*64 + ((tt + cb + 1) & 63)] = v.y;
    tile[(cb+2)*64 + ((tt + cb + 2) & 63)] = v.z;
    tile[(cb+3)*64 + ((tt + cb + 3) & 63)] = v.w;
  }
  __syncthreads();
  #pragma unroll 1
  for (int i = 0; i < 12; i++){
    int idx4 = i*256 + tid;
    int c = idx4 >> 4, pq = idx4 & 15;
    int pb_ = pq*4;
    float4 o;
    o.x = tile[c*64 + ((pb_     + c) & 63)];
    o.y = tile[c*64 + ((pb_ + 1 + c) & 63)];
    o.z = tile[c*64 + ((pb_ + 2 + c) & 63)];
    o.w = tile[c*64 + ((pb_ + 3 + c) & 63)];
    o.x = fminf(fmaxf(o.x, -10.f), 10.f);
    o.y = fminf(fmaxf(o.y, -10.f), 10.f);
    o.z = fminf(fmaxf(o.z, -10.f), 10.f);
    o.w = fminf(fmaxf(o.w, -10.f), 10.f);
    *(float4*)(out + (((size_t)b*192 + c) << 14) + p0 + pb_) = o;
  }
}

extern "C" void kernel_launch(void* const* d_in, const int* in_sizes, int n_in,
                              void* d_out, int out_size, void* d_ws, size_t ws_size,
                              hipStream_t stream){
  (void)in_sizes; (void)n_in; (void)out_size; (void)ws_size;
  const float* x     = (const float*)d_in[0];
  const float* gnw   = (const float*)d_in[1];
  const float* gnb   = (const float*)d_in[2];
  const float* ln1w  = (const float*)d_in[3];
  const float* ln1b  = (const float*)d_in[4];
  const float* qkvw  = (const float*)d_in[5];
  const float* qkvb  = (const float*)d_in[6];
  const float* projw = (const float*)d_in[7];
  const float* projb = (const float*)d_in[8];
  const float* rpb   = (const float*)d_in[9];
  const float* ln2w  = (const float*)d_in[10];
  const float* ln2b  = (const float*)d_in[11];
  const float* fc1w  = (const float*)d_in[12];
  const float* fc1b  = (const float*)d_in[13];
  const float* fc2w  = (const float*)d_in[14];
  const float* fc2b  = (const float*)d_in[15];
  float* out = (float*)d_out;

  float* ws    = (float*)d_ws;
  float* xb2   = ws;                       // [B,H,W,C] fp32
  float* part  = xb2  + 25165824;
  float* stats = part + 3072;
  unsigned short* qkvB = (unsigned short*)(stats + 16);  // [576][192] bf16
  unsigned short* projB = qkvB + 110592;                 // [192][192]
  unsigned short* fc1B  = projB + 36864;                 // [768][192]
  unsigned short* fc2B  = fc1B + 147456;                 // [192][768]
  float* xb    = out;                      // GN output / residual base (d_out until final_k)

  transpose_cast_k<<<432, 256, 0, stream>>>(qkvw, qkvB, 192, 576);
  transpose_cast_k<<<144, 256, 0, stream>>>(projw, projB, 192, 192);
  transpose_cast_k<<<576, 256, 0, stream>>>(fc1w, fc1B, 192, 768);
  transpose_cast_k<<<576, 256, 0, stream>>>(fc2w, fc2B, 768, 192);
  gn_partial<<<1536, 256, 0, stream>>>(x, part);
  gn_final<<<8, 64, 0, stream>>>(part, stats);
  gn_apply<<<2048, 256, 0, stream>>>(x, stats, gnw, gnb, xb);
  attn_kernel<<<2048, 256, 0, stream>>>(xb, xb2, ln1w, ln1b, qkvB, qkvb, projB, projb, rpb);
  mlp_kernel<<<2048, 256, 0, stream>>>(xb, xb2, ln2w, ln2b, fc1B, fc1b, fc2B, fc2b);
  final_k<<<2048, 256, 0, stream>>>(xb2, out);
}

// Round 4
// 1084.148 us; speedup vs baseline: 24.1389x; 1.1747x over previous
//
#include <hip/hip_runtime.h>
#include <cstddef>

typedef __attribute__((ext_vector_type(8))) short bf16x8;
typedef __attribute__((ext_vector_type(4))) float f32x4;

#define DEV __device__ __forceinline__
#define MFMA16(a,b,c) __builtin_amdgcn_mfma_f32_16x16x32_bf16((a),(b),(c),0,0,0)

DEV float bf2f(unsigned int u){ return __uint_as_float(u << 16); }
DEV unsigned short f2bf(float f){
  unsigned int x = __float_as_uint(f);
  x += 0x7fffu + ((x >> 16) & 1u);
  return (unsigned short)(x >> 16);
}
DEV unsigned int pack2(float a, float b){
  return (unsigned int)f2bf(a) | ((unsigned int)f2bf(b) << 16);
}

// ---------------- weight transpose + bf16 cast: out[n][k] = in[k][n] ----------------
__global__ void transpose_cast_k(const float* __restrict__ in, unsigned short* __restrict__ out,
                                 int K, int N){
  int idx = blockIdx.x * 256 + threadIdx.x;
  if (idx < K * N){
    int n = idx / K, k = idx - n * K;
    out[idx] = f2bf(in[k * N + n]);
  }
}

// ---------------- GroupNorm stage 1 ----------------
__global__ void gn_partial(const float* __restrict__ x, float* __restrict__ part){
  int bc = blockIdx.x, tid = threadIdx.x;
  const float4* p = (const float4*)(x + (size_t)bc * 16384);
  float s = 0.f, s2 = 0.f;
  for (int i = tid; i < 4096; i += 256){
    float4 v = p[i];
    s  += v.x + v.y + v.z + v.w;
    s2 += v.x*v.x + v.y*v.y + v.z*v.z + v.w*v.w;
  }
  #pragma unroll
  for (int off = 32; off; off >>= 1){ s += __shfl_down(s, off); s2 += __shfl_down(s2, off); }
  __shared__ float red[8];
  int wid = tid >> 6;
  if ((tid & 63) == 0){ red[wid*2] = s; red[wid*2+1] = s2; }
  __syncthreads();
  if (tid == 0){
    part[bc*2]   = red[0] + red[2] + red[4] + red[6];
    part[bc*2+1] = red[1] + red[3] + red[5] + red[7];
  }
}

// ---------------- GroupNorm stage 2 ----------------
__global__ void gn_final(const float* __restrict__ part, float* __restrict__ stats){
  int b = blockIdx.x, tid = threadIdx.x;
  float s = 0.f, s2 = 0.f;
  for (int c = tid; c < 192; c += 64){
    s  += part[(b*192 + c)*2];
    s2 += part[(b*192 + c)*2 + 1];
  }
  #pragma unroll
  for (int off = 32; off; off >>= 1){ s += __shfl_down(s, off); s2 += __shfl_down(s2, off); }
  if (tid == 0){
    const float inv = 1.f / (192.f * 16384.f);
    float mean = s * inv;
    float var  = s2 * inv - mean*mean;
    stats[b*2]   = mean;
    stats[b*2+1] = rsqrtf(var + 1e-5f);
  }
}

// ---------------- GN apply + NCHW -> NHWC ----------------
__global__ void gn_apply(const float* __restrict__ x, const float* __restrict__ stats,
                         const float* __restrict__ gnw, const float* __restrict__ gnb,
                         float* __restrict__ xb){
  __shared__ float tile[192*64];
  int blk = blockIdx.x, tid = threadIdx.x;
  int b = blk >> 8, p0 = (blk & 255) * 64;
  float mean = stats[b*2], rstd = stats[b*2+1];
  #pragma unroll 1
  for (int i = 0; i < 12; i++){
    int idx4 = i*256 + tid;
    int c = idx4 >> 4, pq = idx4 & 15;
    float4 v = *(const float4*)(x + (((size_t)b*192 + c) << 14) + p0 + pq*4);
    float w  = gnw[c] * rstd;
    float bb = gnb[c] - mean * rstd * gnw[c];
    int pb_ = pq*4;
    tile[c*64 + ((pb_     + c) & 63)] = v.x * w + bb;
    tile[c*64 + ((pb_ + 1 + c) & 63)] = v.y * w + bb;
    tile[c*64 + ((pb_ + 2 + c) & 63)] = v.z * w + bb;
    tile[c*64 + ((pb_ + 3 + c) & 63)] = v.w * w + bb;
  }
  __syncthreads();
  #pragma unroll 1
  for (int i = 0; i < 12; i++){
    int idx4 = i*256 + tid;
    int pix = idx4 / 48, c4 = idx4 - pix*48;
    int cb = c4 * 4;
    float4 o;
    o.x = tile[(cb  )*64 + ((pix + cb    ) & 63)];
    o.y = tile[(cb+1)*64 + ((pix + cb + 1) & 63)];
    o.z = tile[(cb+2)*64 + ((pix + cb + 2) & 63)];
    o.w = tile[(cb+3)*64 + ((pix + cb + 3) & 63)];
    *(float4*)(xb + ((size_t)blk*64 + pix)*192 + cb) = o;
  }
}

// ---------------- fused window attention (MFMA) ----------------
__launch_bounds__(256)
__global__ void attn_kernel(const float* __restrict__ xb, float* __restrict__ xb2,
                            const float* __restrict__ ln1w, const float* __restrict__ ln1b,
                            const unsigned short* __restrict__ qkvB, const float* __restrict__ qkvb,
                            const unsigned short* __restrict__ projB, const float* __restrict__ projb,
                            const float* __restrict__ rpb){
  // LDS layout (union: epilogue fp32 staging aliases the front):
  //   h16  [64][200] bf16   @ 0      (25600 B)  stride 200 -> bank rotation, 2-way max
  //   qk16 [2][2][64*40]    @ 25600  (20480 B)
  //   vT16 [2][32*72]       @ 46080  ( 9216 B)
  //   ps16 [64][72]         @ 55296  ( 9216 B)
  //   regions [64] int      @ 64512  (  256 B)
  //   ep   [64][196] fp32   @ 0      (50176 B)  epilogue only
  __shared__ __align__(16) unsigned char smem[64768];
  unsigned short* h16  = (unsigned short*)smem;
  unsigned short* qk16 = (unsigned short*)(smem + 25600);  // [(s*2+hl)*2560 + ...]
  unsigned short* vT16 = (unsigned short*)(smem + 46080);  // [hl*2304 + d*72 + token]
  unsigned short* ps16 = (unsigned short*)(smem + 55296);  // [token*72 + j]
  int*            regions = (int*)(smem + 64512);
  float*          ep   = (float*)smem;                     // [token*196 + col]

  const int tid = threadIdx.x;
  const int blk = blockIdx.x;
  const int b = blk >> 8, wloc = blk & 255, wh = wloc >> 4, ww = wloc & 15;
  const int lane = tid & 63, wv = tid >> 6;
  const int ln15 = lane & 15, l16 = lane >> 4;
  const f32x4 zero4 = {0.f, 0.f, 0.f, 0.f};

  const int t = tid >> 2, q4 = tid & 3, c0 = q4 * 48;
  const int tr = t >> 3, tc = t & 7;
  const int sh = (wh*8 + tr + 4) & 127, sw = (ww*8 + tc + 4) & 127;
  const float* xrow = xb + (size_t)((((b << 7) + sh) << 7) + sw) * 192;
  float4 xv[12];   // kept live for the epilogue shortcut (no global re-read)

  // ---- LN1 (thread t = token, q4 = channel quarter) ----
  {
    float s = 0.f, s2 = 0.f;
    #pragma unroll
    for (int i = 0; i < 12; i++){
      xv[i] = *(const float4*)(xrow + c0 + i*4);
      s  += xv[i].x + xv[i].y + xv[i].z + xv[i].w;
      s2 += xv[i].x*xv[i].x + xv[i].y*xv[i].y + xv[i].z*xv[i].z + xv[i].w*xv[i].w;
    }
    s  += __shfl_xor(s, 1);  s  += __shfl_xor(s, 2);
    s2 += __shfl_xor(s2, 1); s2 += __shfl_xor(s2, 2);
    const float mean = s * (1.f/192.f);
    const float rstd = rsqrtf(s2 * (1.f/192.f) - mean*mean + 1e-5f);
    #pragma unroll
    for (int i = 0; i < 12; i++){
      int cb = c0 + i*4;
      float v0 = (xv[i].x - mean) * rstd * ln1w[cb  ] + ln1b[cb  ];
      float v1 = (xv[i].y - mean) * rstd * ln1w[cb+1] + ln1b[cb+1];
      float v2 = (xv[i].z - mean) * rstd * ln1w[cb+2] + ln1b[cb+2];
      float v3 = (xv[i].w - mean) * rstd * ln1w[cb+3] + ln1b[cb+3];
      unsigned int* dst = (unsigned int*)(h16 + t*200 + cb);
      dst[0] = pack2(v0, v1);
      dst[1] = pack2(v2, v3);
    }
    if (q4 == 0){
      int gh = wh*8 + tr, gw = ww*8 + tc;
      regions[t] = (gh < 120 ? 0 : (gh < 124 ? 1 : 2)) * 3 + (gw < 120 ? 0 : (gw < 124 ? 1 : 2));
    }
  }
  __syncthreads();

  f32x4 pacc[4][3];
  #pragma unroll
  for (int mt = 0; mt < 4; mt++)
    #pragma unroll
    for (int nt = 0; nt < 3; nt++)
      pacc[mt][nt] = zero4;

  const float scale = 0.17677669529663687f;

  #pragma unroll 1
  for (int hp = 0; hp < 3; hp++){
    const int h0 = hp * 2;
    // ---- phase a: qkv for heads h0,h0+1 (192 cols = 12 tiles; wave does 3) ----
    f32x4 qacc[3][4];
    #pragma unroll
    for (int tt0 = 0; tt0 < 3; tt0++)
      #pragma unroll
      for (int mt = 0; mt < 4; mt++)
        qacc[tt0][mt] = zero4;

    #pragma unroll 1
    for (int tt0 = 0; tt0 < 3; tt0++){
      int tt = wv*3 + tt0;
      int which = tt >> 2, sub = tt & 3;
      int colb = which*192 + h0*32 + sub*16;
      const unsigned short* bp = qkvB + (size_t)(colb + ln15)*192 + l16*8;
      bf16x8 bw[6];
      #pragma unroll
      for (int ks = 0; ks < 6; ks++) bw[ks] = *(const bf16x8*)(bp + ks*32);
      #pragma unroll
      for (int mt = 0; mt < 4; mt++){
        const unsigned short* ap = h16 + (mt*16 + ln15)*200 + l16*8;
        #pragma unroll
        for (int ks = 0; ks < 6; ks++){
          bf16x8 af = *(const bf16x8*)(ap + ks*32);
          qacc[tt0][mt] = MFMA16(af, bw[ks], qacc[tt0][mt]);
        }
      }
    }
    // epilogue: + bias, scatter to q/k/vT LDS (q scaled)
    #pragma unroll 1
    for (int tt0 = 0; tt0 < 3; tt0++){
      int tt = wv*3 + tt0;
      int which = tt >> 2, sub = tt & 3;
      int colg = which*192 + h0*32 + sub*16 + ln15;
      float bias = qkvb[colg];
      int local = sub*16 + ln15;
      int hl = local >> 5, d = local & 31;
      #pragma unroll
      for (int mt = 0; mt < 4; mt++){
        #pragma unroll
        for (int reg = 0; reg < 4; reg++){
          float v = qacc[tt0][mt][reg] + bias;
          int token = mt*16 + l16*4 + reg;
          if (which == 0)      qk16[hl*2560 + token*40 + d]          = f2bf(v * scale);
          else if (which == 1) qk16[(2 + hl)*2560 + token*40 + d]    = f2bf(v);
          else                 vT16[hl*2304 + d*72 + token]          = f2bf(v);
        }
      }
    }
    __syncthreads();

    #pragma unroll 1
    for (int e = 0; e < 2; e++){
      const int h = h0 + e;
      // ---- S = q k^T (wave handles row-tile wv, 4 col-tiles, K=32) ----
      f32x4 sacc[4];
      bf16x8 aq = *(const bf16x8*)(&qk16[e*2560 + (wv*16 + ln15)*40 + l16*8]);
      #pragma unroll
      for (int nt = 0; nt < 4; nt++){
        bf16x8 bk = *(const bf16x8*)(&qk16[(2 + e)*2560 + (nt*16 + ln15)*40 + l16*8]);
        sacc[nt] = MFMA16(aq, bk, zero4);
      }
      // ---- bias + mask ----
      #pragma unroll
      for (int nt = 0; nt < 4; nt++){
        int j_tok = nt*16 + ln15;
        int rj = j_tok >> 3, cj = j_tok & 7;
        int regj = regions[j_tok];
        #pragma unroll
        for (int reg = 0; reg < 4; reg++){
          int i_tok = wv*16 + l16*4 + reg;
          int ri = i_tok >> 3, ci = i_tok & 7;
          float bias = rpb[((ri - rj + 7)*15 + (ci - cj + 7))*6 + h];
          float v = sacc[nt][reg] + bias + ((regions[i_tok] == regj) ? 0.f : -100.f);
          sacc[nt][reg] = v;
        }
      }
      // ---- softmax across 16 lanes (cols) x 4 nt, per reg ----
      float mx[4], sum[4];
      #pragma unroll
      for (int reg = 0; reg < 4; reg++){
        float m = fmaxf(fmaxf(sacc[0][reg], sacc[1][reg]), fmaxf(sacc[2][reg], sacc[3][reg]));
        m = fmaxf(m, __shfl_xor(m, 1));
        m = fmaxf(m, __shfl_xor(m, 2));
        m = fmaxf(m, __shfl_xor(m, 4));
        m = fmaxf(m, __shfl_xor(m, 8));
        mx[reg] = m;
        sum[reg] = 0.f;
      }
      #pragma unroll
      for (int nt = 0; nt < 4; nt++)
        #pragma unroll
        for (int reg = 0; reg < 4; reg++){
          float ex = __expf(sacc[nt][reg] - mx[reg]);
          sacc[nt][reg] = ex;
          sum[reg] += ex;
        }
      #pragma unroll
      for (int reg = 0; reg < 4; reg++){
        float sm = sum[reg];
        sm += __shfl_xor(sm, 1);
        sm += __shfl_xor(sm, 2);
        sm += __shfl_xor(sm, 4);
        sm += __shfl_xor(sm, 8);
        sum[reg] = 1.f / sm;
      }
      // ---- write P (own rows) ----
      #pragma unroll
      for (int nt = 0; nt < 4; nt++)
        #pragma unroll
        for (int reg = 0; reg < 4; reg++)
          ps16[(wv*16 + l16*4 + reg)*72 + nt*16 + ln15] = f2bf(sacc[nt][reg] * sum[reg]);
      // ---- PV (K=64 -> 2 ks steps; 2 col-tiles of d) ----
      f32x4 cacc[2];
      #pragma unroll
      for (int nt2 = 0; nt2 < 2; nt2++) cacc[nt2] = zero4;
      #pragma unroll
      for (int ks = 0; ks < 2; ks++){
        bf16x8 ap = *(const bf16x8*)(&ps16[(wv*16 + ln15)*72 + ks*32 + l16*8]);
        #pragma unroll
        for (int nt2 = 0; nt2 < 2; nt2++){
          bf16x8 bv = *(const bf16x8*)(&vT16[e*2304 + (nt2*16 + ln15)*72 + ks*32 + l16*8]);
          cacc[nt2] = MFMA16(ap, bv, cacc[nt2]);
        }
      }
      // ---- ctx into ps cols 0..31 (own rows; own P no longer needed) ----
      #pragma unroll
      for (int nt2 = 0; nt2 < 2; nt2++)
        #pragma unroll
        for (int reg = 0; reg < 4; reg++)
          ps16[(wv*16 + l16*4 + reg)*72 + nt2*16 + ln15] = f2bf(cacc[nt2][reg]);
      __syncthreads();
      // ---- proj accumulate: out cols [wv*48, +48), K = this head's 32 dims ----
      bf16x8 bw3[3];
      #pragma unroll
      for (int nt3 = 0; nt3 < 3; nt3++)
        bw3[nt3] = *(const bf16x8*)(projB + (size_t)(wv*48 + nt3*16 + ln15)*192 + h*32 + l16*8);
      #pragma unroll
      for (int mt = 0; mt < 4; mt++){
        bf16x8 ac = *(const bf16x8*)(&ps16[(mt*16 + ln15)*72 + l16*8]);
        #pragma unroll
        for (int nt3 = 0; nt3 < 3; nt3++)
          pacc[mt][nt3] = MFMA16(ac, bw3[nt3], pacc[mt][nt3]);
      }
      __syncthreads();
    }
  }
  // ---- epilogue: stage proj result to LDS, write coalesced float4 rows ----
  // (last loop iteration ended with __syncthreads(); smem reusable)
  #pragma unroll
  for (int nt3 = 0; nt3 < 3; nt3++){
    int col = wv*48 + nt3*16 + ln15;
    #pragma unroll
    for (int mt = 0; mt < 4; mt++)
      #pragma unroll
      for (int reg = 0; reg < 4; reg++)
        ep[(mt*16 + l16*4 + reg)*196 + col] = pacc[mt][nt3][reg];
  }
  __syncthreads();
  {
    float* orow = xb2 + (size_t)((((b << 7) + sh) << 7) + sw) * 192;
    #pragma unroll
    for (int i = 0; i < 12; i++){
      float4 pv  = *(float4*)(ep + t*196 + c0 + i*4);
      float4 pb4 = *(const float4*)(projb + c0 + i*4);
      float4 o;
      o.x = xv[i].x + pv.x + pb4.x;
      o.y = xv[i].y + pv.y + pb4.y;
      o.z = xv[i].z + pv.z + pb4.z;
      o.w = xv[i].w + pv.w + pb4.w;
      *(float4*)(orow + c0 + i*4) = o;
    }
  }
}

// ---------------- fused MLP (MFMA): LN2 + fc1 + GELU + fc2 + residuals ----------------
__launch_bounds__(256)
__global__ void mlp_kernel(const float* __restrict__ xb, float* __restrict__ xb2,
                           const float* __restrict__ ln2w, const float* __restrict__ ln2b,
                           const unsigned short* __restrict__ fc1B, const float* __restrict__ fc1b,
                           const unsigned short* __restrict__ fc2B, const float* __restrict__ fc2b){
  // LDS union: aln [64][200] bf16 @0 (25600) | hid [64][136] bf16 @25600 (17408)
  //            ep [64][196] fp32 @0 (50176, epilogue only)
  __shared__ __align__(16) unsigned char smem[50176];
  unsigned short* aln = (unsigned short*)smem;
  unsigned short* hid = (unsigned short*)(smem + 25600);
  float*          ep  = (float*)smem;

  const int tid = threadIdx.x;
  const int lane = tid & 63, wv = tid >> 6;
  const int ln15 = lane & 15, l16 = lane >> 4;
  const size_t p0 = (size_t)blockIdx.x * 64;
  const f32x4 zero4 = {0.f, 0.f, 0.f, 0.f};

  const int t = tid >> 2, q4 = tid & 3, c0 = q4 * 48;
  float4 xv[12];   // xb2 row, kept live for epilogue residual

  // ---- LN2 ----
  {
    const float* xrow2 = xb2 + (p0 + t)*192;
    float s = 0.f, s2 = 0.f;
    #pragma unroll
    for (int i = 0; i < 12; i++){
      xv[i] = *(const float4*)(xrow2 + c0 + i*4);
      s  += xv[i].x + xv[i].y + xv[i].z + xv[i].w;
      s2 += xv[i].x*xv[i].x + xv[i].y*xv[i].y + xv[i].z*xv[i].z + xv[i].w*xv[i].w;
    }
    s  += __shfl_xor(s, 1);  s  += __shfl_xor(s, 2);
    s2 += __shfl_xor(s2, 1); s2 += __shfl_xor(s2, 2);
    const float mean = s * (1.f/192.f);
    const float rstd = rsqrtf(s2 * (1.f/192.f) - mean*mean + 1e-5f);
    #pragma unroll
    for (int i = 0; i < 12; i++){
      int cb = c0 + i*4;
      float v0 = (xv[i].x - mean) * rstd * ln2w[cb  ] + ln2b[cb  ];
      float v1 = (xv[i].y - mean) * rstd * ln2w[cb+1] + ln2b[cb+1];
      float v2 = (xv[i].z - mean) * rstd * ln2w[cb+2] + ln2b[cb+2];
      float v3 = (xv[i].w - mean) * rstd * ln2w[cb+3] + ln2b[cb+3];
      unsigned int* dst = (unsigned int*)(aln + t*200 + cb);
      dst[0] = pack2(v0, v1);
      dst[1] = pack2(v2, v3);
    }
  }
  __syncthreads();

  f32x4 o2[4][3];
  #pragma unroll
  for (int mt = 0; mt < 4; mt++)
    #pragma unroll
    for (int nt = 0; nt < 3; nt++)
      o2[mt][nt] = zero4;

  #pragma unroll 1
  for (int ch = 0; ch < 6; ch++){
    // ---- fc1: wave computes hidden cols [ch*128 + wv*32, +32) for all 64 tokens ----
    f32x4 f1[4][2];
    #pragma unroll
    for (int mt = 0; mt < 4; mt++)
      #pragma unroll
      for (int nt = 0; nt < 2; nt++)
        f1[mt][nt] = zero4;
    #pragma unroll 1
    for (int nt = 0; nt < 2; nt++){
      const unsigned short* bp = fc1B + (size_t)(ch*128 + wv*32 + nt*16 + ln15)*192 + l16*8;
      bf16x8 bw[6];
      #pragma unroll
      for (int ks = 0; ks < 6; ks++) bw[ks] = *(const bf16x8*)(bp + ks*32);
      #pragma unroll
      for (int mt = 0; mt < 4; mt++){
        const unsigned short* ap = aln + (mt*16 + ln15)*200 + l16*8;
        #pragma unroll
        for (int ks = 0; ks < 6; ks++){
          bf16x8 af = *(const bf16x8*)(ap + ks*32);
          f1[mt][nt] = MFMA16(af, bw[ks], f1[mt][nt]);
        }
      }
    }
    // ---- bias + GELU -> hid ----
    #pragma unroll
    for (int nt = 0; nt < 2; nt++){
      int hcol = wv*32 + nt*16 + ln15;
      float b1 = fc1b[ch*128 + hcol];
      #pragma unroll
      for (int mt = 0; mt < 4; mt++){
        #pragma unroll
        for (int reg = 0; reg < 4; reg++){
          float v = f1[mt][nt][reg] + b1;
          float g = 0.5f * v * (1.f + erff(v * 0.7071067811865475f));
          hid[(mt*16 + l16*4 + reg)*136 + hcol] = f2bf(g);
        }
      }
    }
    __syncthreads();
    // ---- fc2 partial: out cols [wv*48, +48), K = 128 chunk ----
    #pragma unroll 1
    for (int ks = 0; ks < 4; ks++){
      bf16x8 bw2[3];
      #pragma unroll
      for (int nt3 = 0; nt3 < 3; nt3++)
        bw2[nt3] = *(const bf16x8*)(fc2B + (size_t)(wv*48 + nt3*16 + ln15)*768 + ch*128 + ks*32 + l16*8);
      #pragma unroll
      for (int mt = 0; mt < 4; mt++){
        bf16x8 af = *(const bf16x8*)(&hid[(mt*16 + ln15)*136 + ks*32 + l16*8]);
        #pragma unroll
        for (int nt3 = 0; nt3 < 3; nt3++)
          o2[mt][nt3] = MFMA16(af, bw2[nt3], o2[mt][nt3]);
      }
    }
    __syncthreads();
  }
  // ---- epilogue: stage to LDS, coalesced float4 read-modify-write ----
  #pragma unroll
  for (int nt3 = 0; nt3 < 3; nt3++){
    int col = wv*48 + nt3*16 + ln15;
    #pragma unroll
    for (int mt = 0; mt < 4; mt++)
      #pragma unroll
      for (int reg = 0; reg < 4; reg++)
        ep[(mt*16 + l16*4 + reg)*196 + col] = o2[mt][nt3][reg];
  }
  __syncthreads();
  {
    const float* xrow = xb + (p0 + t)*192;
    float* orow = xb2 + (p0 + t)*192;
    #pragma unroll
    for (int i = 0; i < 12; i++){
      float4 mv  = *(float4*)(ep + t*196 + c0 + i*4);
      float4 xr  = *(const float4*)(xrow + c0 + i*4);
      float4 fb4 = *(const float4*)(fc2b + c0 + i*4);
      float4 o;
      o.x = xv[i].x + xr.x + fb4.x + mv.x;
      o.y = xv[i].y + xr.y + fb4.y + mv.y;
      o.z = xv[i].z + xr.z + fb4.z + mv.z;
      o.w = xv[i].w + xr.w + fb4.w + mv.w;
      *(float4*)(orow + c0 + i*4) = o;
    }
  }
}

// ---------------- final NHWC -> NCHW + clamp ----------------
__global__ void final_k(const float* __restrict__ xb2, float* __restrict__ out){
  __shared__ float tile[192*64];
  int blk = blockIdx.x, tid = threadIdx.x;
  int b = blk >> 8, p0 = (blk & 255) * 64;
  #pragma unroll 1
  for (int i = 0; i < 12; i++){
    int idx4 = i*256 + tid;
    int tt = idx4 / 48, c4 = idx4 - tt*48;
    int cb = c4 * 4;
    float4 v = *(const float4*)(xb2 + ((size_t)blk*64 + tt)*192 + cb);
    tile[(cb  )*64 + ((tt + cb    ) & 63)] = v.x;
    tile[(cb+1)*64 + ((tt + cb + 1) & 63)] = v.y;
    tile[(cb+2)*64 + ((tt + cb + 2) & 63)] = v.z;
    tile[(cb+3)*64 + ((tt + cb + 3) & 63)] = v.w;
  }
  __syncthreads();
  #pragma unroll 1
  for (int i = 0; i < 12; i++){
    int idx4 = i*256 + tid;
    int c = idx4 >> 4, pq = idx4 & 15;
    int pb_ = pq*4;
    float4 o;
    o.x = tile[c*64 + ((pb_     + c) & 63)];
    o.y = tile[c*64 + ((pb_ + 1 + c) & 63)];
    o.z = tile[c*64 + ((pb_ + 2 + c) & 63)];
    o.w = tile[c*64 + ((pb_ + 3 + c) & 63)];
    o.x = fminf(fmaxf(o.x, -10.f), 10.f);
    o.y = fminf(fmaxf(o.y, -10.f), 10.f);
    o.z = fminf(fmaxf(o.z, -10.f), 10.f);
    o.w = fminf(fmaxf(o.w, -10.f), 10.f);
    *(float4*)(out + (((size_t)b*192 + c) << 14) + p0 + pb_) = o;
  }
}

extern "C" void kernel_launch(void* const* d_in, const int* in_sizes, int n_in,
                              void* d_out, int out_size, void* d_ws, size_t ws_size,
                              hipStream_t stream){
  (void)in_sizes; (void)n_in; (void)out_size; (void)ws_size;
  const float* x     = (const float*)d_in[0];
  const float* gnw   = (const float*)d_in[1];
  const float* gnb   = (const float*)d_in[2];
  const float* ln1w  = (const float*)d_in[3];
  const float* ln1b  = (const float*)d_in[4];
  const float* qkvw  = (const float*)d_in[5];
  const float* qkvb  = (const float*)d_in[6];
  const float* projw = (const float*)d_in[7];
  const float* projb = (const float*)d_in[8];
  const float* rpb   = (const float*)d_in[9];
  const float* ln2w  = (const float*)d_in[10];
  const float* ln2b  = (const float*)d_in[11];
  const float* fc1w  = (const float*)d_in[12];
  const float* fc1b  = (const float*)d_in[13];
  const float* fc2w  = (const float*)d_in[14];
  const float* fc2b  = (const float*)d_in[15];
  float* out = (float*)d_out;

  float* ws    = (float*)d_ws;
  float* xb2   = ws;                       // [B,H,W,C] fp32
  float* part  = xb2  + 25165824;
  float* stats = part + 3072;
  unsigned short* qkvB = (unsigned short*)(stats + 16);  // [576][192] bf16
  unsigned short* projB = qkvB + 110592;                 // [192][192]
  unsigned short* fc1B  = projB + 36864;                 // [768][192]
  unsigned short* fc2B  = fc1B + 147456;                 // [192][768]
  float* xb    = out;                      // GN output / residual base (d_out until final_k)

  transpose_cast_k<<<432, 256, 0, stream>>>(qkvw, qkvB, 192, 576);
  transpose_cast_k<<<144, 256, 0, stream>>>(projw, projB, 192, 192);
  transpose_cast_k<<<576, 256, 0, stream>>>(fc1w, fc1B, 192, 768);
  transpose_cast_k<<<576, 256, 0, stream>>>(fc2w, fc2B, 768, 192);
  gn_partial<<<1536, 256, 0, stream>>>(x, part);
  gn_final<<<8, 64, 0, stream>>>(part, stats);
  gn_apply<<<2048, 256, 0, stream>>>(x, stats, gnw, gnb, xb);
  attn_kernel<<<2048, 256, 0, stream>>>(xb, xb2, ln1w, ln1b, qkvB, qkvb, projB, projb, rpb);
  mlp_kernel<<<2048, 256, 0, stream>>>(xb, xb2, ln2w, ln2b, fc1B, fc1b, fc2B, fc2b);
  final_k<<<2048, 256, 0, stream>>>(xb2, out);
}